// Round 2
// baseline (156.279 us; speedup 1.0000x reference)
//
#include <hip/hip_runtime.h>

#define HIMG 256
#define WIMG 256
#define CCH  32
#define JBOX 64
#define BIMG 8
#define HGT  8
#define CPB  8     // channels per block
#define NCG  (CCH / CPB)
#define NXCD 8
#define LSEG 208   // staged logical cols from xs4: span <= 207 (proven from box bounds)
#define LPAD 216   // physical row: phi(c) = c + (c>>5); phi(207)=213, pad to 216

// R12: break the load-latency convoy (R10/R11 identical 54us despite big
// in-CU changes => bound by per-block global-load latency, not any CU pipe).
// - One block owns all 8 h for one (bj, cg): grid 16384 -> 2048 = exactly
//   8 blocks/CU, all co-resident, no tail.
// - Software pipeline over h with double-buffered LDS: blend(regs->LDS[buf]),
//   ISSUE next-h global loads into regs, raw s_barrier (lgkmcnt only -- no
//   vmcnt drain, so prefetch rides across the barrier), consume(buf).
// - x-taps are h-invariant: computed once per thread (was 8x).
// - Numerics identical to R11 (passed absmax): same skewed conflict-free
//   LDS layout, same ds_read2-adjacent duplicate at group holes.
__global__ __launch_bounds__(256, 8) void roi_kernel(
    const float* __restrict__ img,     // (B, C, HIMG, WIMG)
    const float* __restrict__ boxes,   // (B, J, 5)
    float* __restrict__ res,           // (B, J, C, HGT, max_w)
    float* __restrict__ mask,          // (B, J, max_w)
    int max_w)
{
    __shared__ float sblend[2][CPB][LPAD];   // 13,824 B

    const int d    = blockIdx.x;
    const int slot = d & (NXCD - 1);          // XCD
    const int seq  = d >> 3;                  // 0..255
    const int bj   = slot * ((BIMG * JBOX) / NXCD) + (seq >> 2);
    const int cg   = seq & 3;                 // channel group 0..3
    const int b    = bj >> 6;                 // J = 64
    const int tid  = threadIdx.x;

    const float left = boxes[bj * 5 + 0];
    const float top  = boxes[bj * 5 + 1];
    const float bw   = boxes[bj * 5 + 2] - left;
    const float bh   = boxes[bj * 5 + 3] - top;

    // width = int32(bw/bh * 8) with f32 ops + truncation (matches numpy).
    const int   width  = (int)(bw / bh * 8.0f);
    const float each_w = bw / ((float)width - 1.0f);
    const float each_h = bh / 7.0f;

    const int xs  = max((int)floorf(left), 0);   // <= 40
    const int xs4 = xs & ~3;                     // 16B-aligned window start

    // ---- per-thread x taps (h-invariant, hoisted out of the h loop) ----
    const int  i    = tid;
    const bool have = (i < max_w);
    const bool in_w = (i < width);
    const float x  = __fadd_rn(__fmul_rn((float)i, each_w), left);
    const int   xf = (int)floorf(x);
    const int   x0 = min(max(xf, 0), WIMG - 1);
    const float wx1 = (float)(x0 + 1) - x;
    const float wx0 = x - (float)x0;
    const int lx0 = min(max(x0 - xs4, 0), LSEG - 2);
    const int p0  = lx0 + (lx0 >> 5);            // skewed physical index

    if (cg == 0 && have) {
        mask[(size_t)bj * max_w + i] = in_w ? 1.0f : 0.0f;
    }

    // ---- staging identity (h-invariant): thread covers (chA, l) and (chB, l)
    const int  l   = tid & 63;                   // float4 slot 0..63
    const bool act = (l < 52);                   // 52*4 = 208 cols
    const int  chA = tid >> 6;                   // 0..3
    const int  chB = chA + 4;                    // 4..7
    const int  coloff = xs4 + l * 4;
    const float* base = img + ((size_t)b * CCH + cg * CPB) * (HIMG * WIMG);
    const float* rowA = base + (size_t)chA * (HIMG * WIMG) + coloff;
    const float* rowB = base + (size_t)chB * (HIMG * WIMG) + coloff;

    const int  c   = l * 4;
    const int  pw  = c + (c >> 5);               // skewed write index
    const bool hole = act && ((l & 7) == 0) && (l != 0);

    const size_t c_stride = (size_t)HGT * max_w;
    float* resp0 = res + (((size_t)bj * CCH + cg * CPB) * HGT) * (size_t)max_w + i;

    // per-h y taps (block-uniform). Separate mul/add roundings (match numpy).
    int y0n, y1n; float wy0n, wy1n;
    auto taps = [&](int h) {
        const float y  = __fadd_rn(__fmul_rn((float)h, each_h), top);
        const int   yf = (int)floorf(y);
        y0n = min(max(yf,     0), HIMG - 1);
        y1n = min(max(yf + 1, 0), HIMG - 1);
        wy1n = (float)y1n - y;
        wy0n = y - (float)y0n;
    };

    float4 qA0, qA1, qB0, qB1;                   // prefetched rows (regs)
    auto issue = [&](int y0, int y1) {
        if (act) {
            qA0 = *reinterpret_cast<const float4*>(rowA + (size_t)y0 * WIMG); // 16B-aligned
            qA1 = *reinterpret_cast<const float4*>(rowA + (size_t)y1 * WIMG);
            qB0 = *reinterpret_cast<const float4*>(rowB + (size_t)y0 * WIMG);
            qB1 = *reinterpret_cast<const float4*>(rowB + (size_t)y1 * WIMG);
        }
    };

    // prologue: prefetch h=0
    taps(0);
    issue(y0n, y1n);
    float w0c = wy0n, w1c = wy1n;

    #pragma unroll
    for (int h = 0; h < HGT; ++h) {
        const int buf = h & 1;

        // blend current-h rows (waits vmcnt for the prefetch; consume of the
        // previous h already ran, covering the latency) and write LDS.
        if (act) {
            const float a0 = qA0.x * w1c + qA1.x * w0c;
            const float a1 = qA0.y * w1c + qA1.y * w0c;
            const float a2 = qA0.z * w1c + qA1.z * w0c;
            const float a3 = qA0.w * w1c + qA1.w * w0c;
            float* wp = &sblend[buf][chA][pw];
            wp[0] = a0; wp[1] = a1; wp[2] = a2; wp[3] = a3;
            if (hole) wp[-1] = a0;               // duplicate for adjacency
            const float b0 = qB0.x * w1c + qB1.x * w0c;
            const float b1 = qB0.y * w1c + qB1.y * w0c;
            const float b2 = qB0.z * w1c + qB1.z * w0c;
            const float b3 = qB0.w * w1c + qB1.w * w0c;
            float* wq = &sblend[buf][chB][pw];
            wq[0] = b0; wq[1] = b1; wq[2] = b2; wq[3] = b3;
            if (hole) wq[-1] = b0;
        }

        // issue next-h loads NOW; they stay in flight across the barrier
        // (raw s_barrier below does not drain vmcnt).
        if (h < HGT - 1) {
            taps(h + 1);
            issue(y0n, y1n);
        }

        // LDS writes must be visible to the block; prefetch loads need not be.
        asm volatile("s_waitcnt lgkmcnt(0)" ::: "memory");
        __builtin_amdgcn_s_barrier();
        __builtin_amdgcn_sched_barrier(0);

        if (have) {
            float* resp = resp0 + (size_t)h * max_w;
            const float* rp = &sblend[buf][0][p0];
            #pragma unroll
            for (int cc = 0; cc < CPB; ++cc) {
                const float v0 = rp[0];          // ds_read2_b32 pair
                const float v1 = rp[1];
                const float val = v0 * wx1 + v1 * wx0;
                resp[(size_t)cc * c_stride] = in_w ? val : 0.0f;
                rp += LPAD;
            }
        }

        w0c = wy0n; w1c = wy1n;
        // WAR on sblend[buf] (rewritten at h+2) is protected by the barrier
        // at h+1; no second barrier needed.
    }
}

extern "C" void kernel_launch(void* const* d_in, const int* in_sizes, int n_in,
                              void* d_out, int out_size, void* d_ws, size_t ws_size,
                              hipStream_t stream) {
    const float* img   = (const float*)d_in[0];
    const float* boxes = (const float*)d_in[1];
    float* out = (float*)d_out;

    const int per_w = BIMG * JBOX * CCH * HGT + BIMG * JBOX;  // 131584
    const int max_w = out_size / per_w;

    float* res  = out;
    float* mask = out + (size_t)BIMG * JBOX * CCH * HGT * max_w;

    const int blocks = BIMG * JBOX * NCG;   // 2048 = 8 blocks/CU, all resident
    roi_kernel<<<blocks, 256, 0, stream>>>(img, boxes, res, mask, max_w);
}

// Round 3
// 156.178 us; speedup vs baseline: 1.0006x; 1.0006x over previous
//
#include <hip/hip_runtime.h>

#define HIMG 256
#define WIMG 256
#define CCH  32
#define JBOX 64
#define BIMG 8
#define HGT  8
#define CPB  8     // channels per block
#define NCG  (CCH / CPB)
#define NXCD 8
#define LSEG 208   // staged logical cols from xs4: span <= 207 (proven from box bounds)
#define LPAD 216   // physical row: phi(c) = c + (c>>5); phi(207)=213, pad to 216

// R13: make the prefetch REAL. R12's VGPR=24 proves the allocator collapsed
// the 1-deep pipeline (one set alone is 16 VGPR) -> load->use distance ~0,
// per-block serial HBM misses remained. This version:
// - TWO named prefetch sets (no arrays): set consumed at step h was issued
//   at step h-2 => coverage ~2 consumes + 1 blend + 2 barriers >= ~600 cy.
// - sched_barrier(0) after each issue pins the loads early; counted vmcnt
//   (emitted per register dependence) lets the newer set stay in flight.
// - Everything else identical to R12 (grid 2048 = 8 blocks/CU, skewed
//   conflict-free LDS, y-blend at staging, uniform control flow to barriers).
__global__ __launch_bounds__(256, 8) void roi_kernel(
    const float* __restrict__ img,     // (B, C, HIMG, WIMG)
    const float* __restrict__ boxes,   // (B, J, 5)
    float* __restrict__ res,           // (B, J, C, HGT, max_w)
    float* __restrict__ mask,          // (B, J, max_w)
    int max_w)
{
    __shared__ float sblend[2][CPB][LPAD];   // 13,824 B

    const int d    = blockIdx.x;
    const int slot = d & (NXCD - 1);          // XCD
    const int seq  = d >> 3;                  // 0..255
    const int bj   = slot * ((BIMG * JBOX) / NXCD) + (seq >> 2);
    const int cg   = seq & 3;                 // channel group 0..3
    const int b    = bj >> 6;                 // J = 64
    const int tid  = threadIdx.x;

    const float left = boxes[bj * 5 + 0];
    const float top  = boxes[bj * 5 + 1];
    const float bw   = boxes[bj * 5 + 2] - left;
    const float bh   = boxes[bj * 5 + 3] - top;

    // width = int32(bw/bh * 8) with f32 ops + truncation (matches numpy).
    const int   width  = (int)(bw / bh * 8.0f);
    const float each_w = bw / ((float)width - 1.0f);
    const float each_h = bh / 7.0f;

    const int xs  = max((int)floorf(left), 0);   // <= 40
    const int xs4 = xs & ~3;                     // 16B-aligned window start

    // ---- per-thread x taps (h-invariant) ----
    const int  i    = tid;
    const bool have = (i < max_w);
    const bool in_w = (i < width);
    const float x  = __fadd_rn(__fmul_rn((float)i, each_w), left);
    const int   xf = (int)floorf(x);
    const int   x0 = min(max(xf, 0), WIMG - 1);
    const float wx1 = (float)(x0 + 1) - x;
    const float wx0 = x - (float)x0;
    const int lx0 = min(max(x0 - xs4, 0), LSEG - 2);
    const int p0  = lx0 + (lx0 >> 5);            // skewed physical index

    if (cg == 0 && have) {
        mask[(size_t)bj * max_w + i] = in_w ? 1.0f : 0.0f;
    }

    // ---- staging identity (h-invariant): thread covers (chA, l) and (chB, l)
    const int  l   = tid & 63;                   // float4 slot 0..63
    const bool act = (l < 52);                   // 52*4 = 208 cols
    const int  chA = tid >> 6;                   // 0..3
    const int  chB = chA + 4;                    // 4..7
    const int  coloff = xs4 + l * 4;
    const float* base = img + ((size_t)b * CCH + cg * CPB) * (HIMG * WIMG);
    const float* rowA = base + (size_t)chA * (HIMG * WIMG) + coloff;
    const float* rowB = base + (size_t)chB * (HIMG * WIMG) + coloff;

    const int  c   = l * 4;
    const int  pw  = c + (c >> 5);               // skewed write index
    const bool hole = act && ((l & 7) == 0) && (l != 0);

    const size_t c_stride = (size_t)HGT * max_w;
    float* resp0 = res + (((size_t)bj * CCH + cg * CPB) * HGT) * (size_t)max_w + i;

    // per-h y taps (block-uniform). Separate mul/add roundings (match numpy).
    int y0n, y1n; float wy0n, wy1n;
    auto taps = [&](int h) {
        const float y  = __fadd_rn(__fmul_rn((float)h, each_h), top);
        const int   yf = (int)floorf(y);
        y0n = min(max(yf,     0), HIMG - 1);
        y1n = min(max(yf + 1, 0), HIMG - 1);
        wy1n = (float)y1n - y;
        wy0n = y - (float)y0n;
    };

    // Two named prefetch sets (16 VGPR each) -- 2-deep pipeline.
    float4 q0A0, q0A1, q0B0, q0B1;
    float4 q1A0, q1A1, q1B0, q1B1;
    float  w0y0, w0y1, w1y0, w1y1;

#define ISSUE(Q)                                                              \
    do { if (act) {                                                           \
        Q##A0 = *reinterpret_cast<const float4*>(rowA + (size_t)y0n * WIMG);  \
        Q##A1 = *reinterpret_cast<const float4*>(rowA + (size_t)y1n * WIMG);  \
        Q##B0 = *reinterpret_cast<const float4*>(rowB + (size_t)y0n * WIMG);  \
        Q##B1 = *reinterpret_cast<const float4*>(rowB + (size_t)y1n * WIMG);  \
    } } while (0)

#define STEP(H, Q, WY0, WY1)                                                  \
    do {                                                                      \
        /* blend set Q (vmcnt wait is counted: only this set's 4 loads) */    \
        if (act) {                                                            \
            const float a0 = Q##A0.x * (WY1) + Q##A1.x * (WY0);               \
            const float a1 = Q##A0.y * (WY1) + Q##A1.y * (WY0);               \
            const float a2 = Q##A0.z * (WY1) + Q##A1.z * (WY0);               \
            const float a3 = Q##A0.w * (WY1) + Q##A1.w * (WY0);               \
            float* wp = &sblend[(H) & 1][chA][pw];                            \
            wp[0] = a0; wp[1] = a1; wp[2] = a2; wp[3] = a3;                   \
            if (hole) wp[-1] = a0;                                            \
            const float b0 = Q##B0.x * (WY1) + Q##B1.x * (WY0);               \
            const float b1 = Q##B0.y * (WY1) + Q##B1.y * (WY0);               \
            const float b2 = Q##B0.z * (WY1) + Q##B1.z * (WY0);               \
            const float b3 = Q##B0.w * (WY1) + Q##B1.w * (WY0);               \
            float* wq = &sblend[(H) & 1][chB][pw];                            \
            wq[0] = b0; wq[1] = b1; wq[2] = b2; wq[3] = b3;                   \
            if (hole) wq[-1] = b0;                                            \
        }                                                                     \
        /* refill set Q for step H+2; pin the loads here so the scheduler */  \
        /* cannot sink them toward their use two steps later.            */   \
        if ((H) + 2 < HGT) {                                                  \
            taps((H) + 2);                                                    \
            WY0 = wy0n; WY1 = wy1n;                                           \
            ISSUE(Q);                                                         \
            __builtin_amdgcn_sched_barrier(0);                                \
        }                                                                     \
        asm volatile("s_waitcnt lgkmcnt(0)" ::: "memory");                    \
        __builtin_amdgcn_s_barrier();                                         \
        __builtin_amdgcn_sched_barrier(0);                                    \
        if (have) {                                                           \
            float* resp = resp0 + (size_t)(H) * max_w;                        \
            const float* rp = &sblend[(H) & 1][0][p0];                        \
            _Pragma("unroll")                                                 \
            for (int cc = 0; cc < CPB; ++cc) {                                \
                const float v0 = rp[0];          /* ds_read2_b32 pair */      \
                const float v1 = rp[1];                                       \
                const float val = v0 * wx1 + v1 * wx0;                        \
                resp[(size_t)cc * c_stride] = in_w ? val : 0.0f;              \
                rp += LPAD;                                                   \
            }                                                                 \
        }                                                                     \
    } while (0)

    // prologue: fill both sets (h=0 into q0, h=1 into q1), 8 loads in flight
    taps(0); w0y0 = wy0n; w0y1 = wy1n; ISSUE(q0);
    taps(1); w1y0 = wy0n; w1y1 = wy1n; ISSUE(q1);
    __builtin_amdgcn_sched_barrier(0);

    STEP(0, q0, w0y0, w0y1);
    STEP(1, q1, w1y0, w1y1);
    STEP(2, q0, w0y0, w0y1);
    STEP(3, q1, w1y0, w1y1);
    STEP(4, q0, w0y0, w0y1);
    STEP(5, q1, w1y0, w1y1);
    STEP(6, q0, w0y0, w0y1);
    STEP(7, q1, w1y0, w1y1);

#undef STEP
#undef ISSUE
}

extern "C" void kernel_launch(void* const* d_in, const int* in_sizes, int n_in,
                              void* d_out, int out_size, void* d_ws, size_t ws_size,
                              hipStream_t stream) {
    const float* img   = (const float*)d_in[0];
    const float* boxes = (const float*)d_in[1];
    float* out = (float*)d_out;

    const int per_w = BIMG * JBOX * CCH * HGT + BIMG * JBOX;  // 131584
    const int max_w = out_size / per_w;

    float* res  = out;
    float* mask = out + (size_t)BIMG * JBOX * CCH * HGT * max_w;

    const int blocks = BIMG * JBOX * NCG;   // 2048 = 8 blocks/CU, all resident
    roi_kernel<<<blocks, 256, 0, stream>>>(img, boxes, res, mask, max_w);
}

// Round 4
// 153.340 us; speedup vs baseline: 1.0192x; 1.0185x over previous
//
#include <hip/hip_runtime.h>

#define HIMG 256
#define WIMG 256
#define CCH  32
#define JBOX 64
#define BIMG 8
#define HGT  8
#define CPB  4     // channels per block
#define NCG  (CCH / CPB)   // 8 channel groups
#define NXCD 8
#define LROW 256   // floats per staged LDS row (1 KB = 64 lanes x 16 B)

// R14: un-collapsible software pipeline via global_load_lds + counted vmcnt.
// R12/R13 (VGPR=24/32) proved the allocator collapses register-tracked
// prefetch; DMA-to-LDS has no dest register to track and the wait is our
// inline-asm s_waitcnt vmcnt(2), so the pipeline survives codegen (T3/T4).
// - Raw row staging (no pre-blend); y-blend moved to consume (+2 FMA, VALU idle).
// - CPB=4, grid 4096, LDS 16KB -> 8 blocks/CU = 32 waves = FULL occupancy.
// - Per iter: vmcnt(2) [next batch stays in flight], s_barrier, consume,
//   s_barrier (WAR), DMA-issue batch h+2 into freed buffer.
// - vmcnt(2) is robust: the in-flight batch is always the youngest 2 VMEM
//   ops per wave, regardless of how many stores a wave issued (wave 3 has
//   zero active consume lanes and may branch around its stores).
typedef __attribute__((address_space(3))) float lds_f;
typedef const __attribute__((address_space(1))) float glb_f;

#define WAITV2() do { asm volatile("s_waitcnt vmcnt(2)" ::: "memory"); \
                      __builtin_amdgcn_sched_barrier(0); } while (0)

__global__ __launch_bounds__(256, 8) void roi_kernel(
    const float* __restrict__ img,     // (B, C, HIMG, WIMG)
    const float* __restrict__ boxes,   // (B, J, 5)
    float* __restrict__ res,           // (B, J, C, HGT, max_w)
    float* __restrict__ mask,          // (B, J, max_w)
    int max_w)
{
    __shared__ float sbuf[2][CPB][2][LROW];   // 16,384 B

    const int d    = blockIdx.x;
    const int slot = d & (NXCD - 1);          // XCD
    const int seq  = d >> 3;                  // 0..511
    const int bj   = slot * ((BIMG * JBOX) / NXCD) + (seq >> 3);
    const int cg   = seq & 7;                 // channel group 0..7 (4 ch each)
    const int b    = bj >> 6;                 // J = 64
    const int tid  = threadIdx.x;

    const float left = boxes[bj * 5 + 0];
    const float top  = boxes[bj * 5 + 1];
    const float bw   = boxes[bj * 5 + 2] - left;
    const float bh   = boxes[bj * 5 + 3] - top;

    // width = int32(bw/bh * 8) with f32 ops + truncation (matches numpy).
    const int   width  = (int)(bw / bh * 8.0f);
    const float each_w = bw / ((float)width - 1.0f);
    const float each_h = bh / 7.0f;

    const int xs  = max((int)floorf(left), 0);   // <= 40
    const int xs4 = xs & ~3;                     // 16B-aligned window start

    // ---- per-thread x taps (h-invariant) ----
    const int  i    = tid;
    const bool have = (i < max_w);
    const bool in_w = (i < width);
    const float x  = __fadd_rn(__fmul_rn((float)i, each_w), left);
    const int   xf = (int)floorf(x);
    const int   x0 = min(max(xf, 0), WIMG - 1);
    const float wx1 = (float)(x0 + 1) - x;
    const float wx0 = x - (float)x0;
    const int   lx0 = min(max(x0 - xs4, 0), 206);   // window pos, lx0+1 <= 207

    if (cg == 0 && have) {
        mask[(size_t)bj * max_w + i] = in_w ? 1.0f : 0.0f;
    }

    // ---- staging identity: wave wv stages channel (cg*4 + wv), rows y0/y1.
    // Per-lane global src (16B granule, clamped inside the 1KB image row);
    // LDS dest is wave-uniform base, HW scatters lane i -> base + i*16.
    const int wv   = tid >> 6;                // 0..3, wave-uniform
    const int lane = tid & 63;
    const float* chbase =
        img + (size_t)(b * CCH + cg * CPB + wv) * (HIMG * WIMG);
    const int offc = min(xs4 + 4 * lane, WIMG - 4);  // float col, 16B-aligned

    auto issue_batch = [&](int h, int bf) {
        const float yh  = __fadd_rn(__fmul_rn((float)h, each_h), top);
        const int   yfl = (int)floorf(yh);
        const int   ya  = min(max(yfl,     0), HIMG - 1);
        const int   yb  = min(max(yfl + 1, 0), HIMG - 1);
        const float* s0 = chbase + (size_t)ya * WIMG + offc;
        const float* s1 = chbase + (size_t)yb * WIMG + offc;
        __builtin_amdgcn_global_load_lds((glb_f*)s0, (lds_f*)&sbuf[bf][wv][0][0], 16, 0, 0);
        __builtin_amdgcn_global_load_lds((glb_f*)s1, (lds_f*)&sbuf[bf][wv][1][0], 16, 0, 0);
    };

    // prologue: batches for h=0 and h=1 in flight (4 DMA ops/wave)
    issue_batch(0, 0);
    issue_batch(1, 1);
    __builtin_amdgcn_sched_barrier(0);

    float* resp0 = res + ((size_t)(bj * CCH + cg * CPB) * HGT) * (size_t)max_w + i;
    const size_t c_stride = (size_t)HGT * max_w;

    #pragma unroll
    for (int h = 0; h < HGT; ++h) {
        const int bf = h & 1;

        // own batch(h) landed (batch(h+1) = youngest 2 ops stays in flight);
        // barrier makes all four waves' rows visible.
        WAITV2();
        __builtin_amdgcn_s_barrier();
        __builtin_amdgcn_sched_barrier(0);

        if (have) {
            // y taps for this h (block-uniform; separate roundings = numpy).
            const float yh  = __fadd_rn(__fmul_rn((float)h, each_h), top);
            const int   yfl = (int)floorf(yh);
            const int   ya  = min(max(yfl,     0), HIMG - 1);
            const int   yb  = min(max(yfl + 1, 0), HIMG - 1);
            const float wy1 = (float)yb - yh;
            const float wy0 = yh - (float)ya;
            const float wa  = wx1 * wy1;
            const float wb_ = wx1 * wy0;
            const float wc_ = wx0 * wy1;
            const float wd_ = wx0 * wy0;
            float* resp = resp0 + (size_t)h * max_w;
            #pragma unroll
            for (int c = 0; c < CPB; ++c) {
                const float v00 = sbuf[bf][c][0][lx0];      // ds_read2_b32
                const float v01 = sbuf[bf][c][0][lx0 + 1];
                const float v10 = sbuf[bf][c][1][lx0];      // ds_read2_b32
                const float v11 = sbuf[bf][c][1][lx0 + 1];
                // identical term order/grouping to R11-R13 (passed absmax):
                const float val = v00 * wa + v10 * wb_ + v01 * wc_ + v11 * wd_;
                resp[(size_t)c * c_stride] = in_w ? val : 0.0f;
            }
        }

        // all waves done READING buf bf before its DMA refill is issued.
        __builtin_amdgcn_sched_barrier(0);
        __builtin_amdgcn_s_barrier();
        __builtin_amdgcn_sched_barrier(0);

        if (h + 2 < HGT) {
            issue_batch(h + 2, bf);
            __builtin_amdgcn_sched_barrier(0);
        }
    }
}

extern "C" void kernel_launch(void* const* d_in, const int* in_sizes, int n_in,
                              void* d_out, int out_size, void* d_ws, size_t ws_size,
                              hipStream_t stream) {
    const float* img   = (const float*)d_in[0];
    const float* boxes = (const float*)d_in[1];
    float* out = (float*)d_out;

    const int per_w = BIMG * JBOX * CCH * HGT + BIMG * JBOX;  // 131584
    const int max_w = out_size / per_w;

    float* res  = out;
    float* mask = out + (size_t)BIMG * JBOX * CCH * HGT * max_w;

    const int blocks = BIMG * JBOX * NCG;   // 4096; 16KB LDS -> 8 blocks/CU
    roi_kernel<<<blocks, 256, 0, stream>>>(img, boxes, res, mask, max_w);
}